// Round 27
// baseline (178.108 us; speedup 1.0000x reference)
//
#include <hip/hip_runtime.h>

constexpr int N = 100000;   // nodes
constexpr int E = 2000000;  // edges per etype
constexpr int D = 256;      // in dim
constexpr int C = 16;       // out dim
constexpr int R = 4;        // etypes
constexpr int NCOL = R * C;             // 64 fused gemm output columns
constexpr int TOT = R * E;              // 8M edges total

constexpr int BKN = 256;                       // nodes per coarse bucket
constexpr int NBUK = (N + BKN - 1) / BKN;      // 391 buckets
constexpr int EPB = 16384;                     // edges per sort block
constexpr int NBLK = (E + EPB - 1) / EPB;      // 123 sort blocks per etype
constexpr int NROWS = R * NBUK;                // 1564 hist rows
constexpr int HLEN = NROWS * NBLK;             // 192,372 hist entries
constexpr int SCAN_ELEMS = 2048;               // per scan1 block (256 thr x 8)
constexpr int SCAN_NBLK = (HLEN + SCAN_ELEMS - 1) / SCAN_ELEMS;  // 94
constexpr int CAP = 3328;                      // accum HALF-pass cap (15 sigma)
constexpr int CHK = 4096;                      // scatter chunk (records)
constexpr int AGRID = ((NBUK + 1) / 2) * 8;    // 1568 accum blocks (XCD-affine)

typedef __attribute__((ext_vector_type(8))) short short8;
typedef __attribute__((ext_vector_type(8))) unsigned short u16x8;
typedef __attribute__((ext_vector_type(4))) float f32x4;
typedef __attribute__((ext_vector_type(4))) int i32x4;

__device__ __forceinline__ float bf2f(unsigned short h) {
    return __uint_as_float(((unsigned int)h) << 16);
}
__device__ __forceinline__ unsigned short f2bf(float f) {
    unsigned int x = __float_as_uint(f);
    x += 0x7FFFu + ((x >> 16) & 1u);   // round-to-nearest-even
    return (unsigned short)(x >> 16);
}

// ---------------------------------------------------------------------------
// Pack W (R,D,C) + implicit fused-col layout into MFMA B-fragment order.
// ---------------------------------------------------------------------------
__global__ void wt_kernel(const float* __restrict__ W, short8* __restrict__ wtb) {
    const int idx = blockIdx.x * blockDim.x + threadIdx.x;
    if (idx >= 8 * 4 * 64) return;
    const int lane = idx & 63;
    const int ct   = (idx >> 6) & 3;
    const int ks   = idx >> 8;
    const int r = ct, c = lane & 15;
    const int kbase = ks * 32 + (lane >> 4) * 8;
    short8 v;
#pragma unroll
    for (int j = 0; j < 8; ++j)
        v[j] = (short)f2bf(W[(size_t)r * D * C + (size_t)(kbase + j) * C + c]);
    wtb[idx] = v;
}

// ---------------------------------------------------------------------------
// MFMA bf16 GEMM with LDS-staged A: whb[r][n][c] = bf16(feat@W_r + b_r).
// ---------------------------------------------------------------------------
__global__ __launch_bounds__(256) void gemm_kernel(
    const f32x4* __restrict__ feat4, const short8* __restrict__ wtb,
    const float* __restrict__ b, unsigned short* __restrict__ whb) {
    __shared__ unsigned short alds[64 * 272];   // 34.8 KB
    const int t   = threadIdx.x;
    const int n0  = blockIdx.x * 64;

#pragma unroll
    for (int j = 0; j < 16; ++j) {
        const int idx = t + j * 256;            // 0..4095
        const int row = idx >> 6, k4 = idx & 63;
        const int grow = n0 + row;
        const int lrow = (grow < N) ? grow : (N - 1);
        const f32x4 v = __builtin_nontemporal_load(&feat4[(size_t)lrow * 64 + k4]);
        ushort4 u;
        u.x = f2bf(v.x); u.y = f2bf(v.y); u.z = f2bf(v.z); u.w = f2bf(v.w);
        *(ushort4*)&alds[row * 272 + k4 * 4] = u;
    }
    __syncthreads();

    const int lane = t & 63;
    const int wv   = t >> 6;
    const int wrow = wv * 16 + (lane & 15);
    const int kblk = lane >> 4;

    f32x4 acc0 = {0.f, 0.f, 0.f, 0.f};
    f32x4 acc1 = acc0, acc2 = acc0, acc3 = acc0;

#pragma unroll
    for (int ks = 0; ks < 8; ++ks) {
        const short8 af = *(const short8*)&alds[wrow * 272 + ks * 32 + kblk * 8];
        const short8 b0 = wtb[(ks * 4 + 0) * 64 + lane];
        const short8 b1 = wtb[(ks * 4 + 1) * 64 + lane];
        const short8 b2 = wtb[(ks * 4 + 2) * 64 + lane];
        const short8 b3 = wtb[(ks * 4 + 3) * 64 + lane];
        acc0 = __builtin_amdgcn_mfma_f32_16x16x32_bf16(af, b0, acc0, 0, 0, 0);
        acc1 = __builtin_amdgcn_mfma_f32_16x16x32_bf16(af, b1, acc1, 0, 0, 0);
        acc2 = __builtin_amdgcn_mfma_f32_16x16x32_bf16(af, b2, acc2, 0, 0, 0);
        acc3 = __builtin_amdgcn_mfma_f32_16x16x32_bf16(af, b3, acc3, 0, 0, 0);
    }

    const int c    = lane & 15;
    const int rowb = n0 + wv * 16 + (lane >> 4) * 4;
    const float bias0 = b[ 0 + c];
    const float bias1 = b[16 + c];
    const float bias2 = b[32 + c];
    const float bias3 = b[48 + c];
#pragma unroll
    for (int reg = 0; reg < 4; ++reg) {
        const int gr = rowb + reg;
        if (gr < N) {
            whb[((size_t)0 * N + gr) * 16 + c] = f2bf(acc0[reg] + bias0);
            whb[((size_t)1 * N + gr) * 16 + c] = f2bf(acc1[reg] + bias1);
            whb[((size_t)2 * N + gr) * 16 + c] = f2bf(acc2[reg] + bias2);
            whb[((size_t)3 * N + gr) * 16 + c] = f2bf(acc3[reg] + bias3);
        }
    }
}

// ---------------------------------------------------------------------------
// Sort pass 1 (all etypes, one launch): per-block LDS histogram of dst>>8.
// Vector fast path; guarded scalar tail (123*16384 > E).
// ---------------------------------------------------------------------------
__global__ __launch_bounds__(256) void hist_kernel(const int* __restrict__ dst,
                                                   int* __restrict__ hist) {
    __shared__ int hcnt[NBUK];
    const int t = threadIdx.x;
    const int r = blockIdx.y;
    for (int i = t; i < NBUK; i += 256) hcnt[i] = 0;
    __syncthreads();
    const int e0 = blockIdx.x * EPB;
    if (E - e0 >= EPB) {
        const i32x4* d4 = (const i32x4*)(dst + (size_t)r * E + e0);
#pragma unroll
        for (int j = 0; j < EPB / 1024; ++j) {
            const i32x4 d = __builtin_nontemporal_load(&d4[t + j * 256]);
            atomicAdd(&hcnt[d.x >> 8], 1);
            atomicAdd(&hcnt[d.y >> 8], 1);
            atomicAdd(&hcnt[d.z >> 8], 1);
            atomicAdd(&hcnt[d.w >> 8], 1);
        }
    } else {
        const int* d = dst + (size_t)r * E;
        for (int e = e0 + t; e < E; e += 256)
            atomicAdd(&hcnt[d[e] >> 8], 1);
    }
    __syncthreads();
    for (int i = t; i < NBUK; i += 256)
        hist[(size_t)(r * NBUK + i) * NBLK + blockIdx.x] = hcnt[i];
}

// ---------------------------------------------------------------------------
// Global exclusive scan over HLEN entries (2048 per scan1 block).
// ---------------------------------------------------------------------------
__global__ __launch_bounds__(256) void scan1_kernel(int* __restrict__ data,
                                                    int* __restrict__ partials) {
    __shared__ int sh[256];
    const int t = threadIdx.x;
    const int idx = blockIdx.x * SCAN_ELEMS + t * 8;
    int v[8];
#pragma unroll
    for (int j = 0; j < 8; ++j)
        v[j] = (idx + j < HLEN) ? data[idx + j] : 0;
    int s = 0;
#pragma unroll
    for (int j = 0; j < 8; ++j) s += v[j];
    sh[t] = s;
    __syncthreads();
    for (int off = 1; off < 256; off <<= 1) {
        int x = (t >= off) ? sh[t - off] : 0;
        __syncthreads();
        sh[t] += x;
        __syncthreads();
    }
    int run = sh[t] - s;
    if (t == 255) partials[blockIdx.x] = sh[255];
#pragma unroll
    for (int j = 0; j < 8; ++j) {
        if (idx + j < HLEN) data[idx + j] = run;
        run += v[j];
    }
}

__global__ __launch_bounds__(1024) void scan2_kernel(int* __restrict__ partials, int n) {
    __shared__ int sh[1024];
    const int t = threadIdx.x;
    int a = (2 * t     < n) ? partials[2 * t]     : 0;
    int b = (2 * t + 1 < n) ? partials[2 * t + 1] : 0;
    const int s = a + b;
    sh[t] = s;
    __syncthreads();
    for (int off = 1; off < 1024; off <<= 1) {
        int x = (t >= off) ? sh[t - off] : 0;
        __syncthreads();
        sh[t] += x;
        __syncthreads();
    }
    const int excl = sh[t] - s;
    if (2 * t     < n) partials[2 * t]     = excl;
    if (2 * t + 1 < n) partials[2 * t + 1] = excl + a;
}

__global__ void scan3_kernel(int* __restrict__ data, const int* __restrict__ partials) {
    const int i = blockIdx.x * blockDim.x + threadIdx.x;
    if (i < HLEN) data[i] += partials[i / SCAN_ELEMS];
}

// ---------------------------------------------------------------------------
// Sort pass 2 (grid NBLK x R), chunk-sorted bursts (CHK=4096, 391 coarse
// bins). SPLIT 6B records: sorted_sd = src | (dst&255)<<20 (4B),
// sorted_w = bf16(ew) (2B). Both written in bucket-run bursts.
// ---------------------------------------------------------------------------
__global__ __launch_bounds__(512) void scatter_kernel(const int* __restrict__ src,
                                                      const int* __restrict__ dst,
                                                      const float* __restrict__ ew,
                                                      const int* __restrict__ hist,
                                                      int* __restrict__ sorted_sd,
                                                      unsigned short* __restrict__ sorted_w) {
    __shared__ int2 lrec[CHK];                  // 32 KB: {sd, bf16w}
    __shared__ int  lidx[CHK];                  // 16 KB: i | b<<16
    __shared__ short lbkt[CHK];                 // 8 KB
    __shared__ int gcur[NBUK];                  // running global cursors
    __shared__ int loff[NBUK + 1];
    __shared__ int lcnt[NBUK];
    const int t = threadIdx.x;
    const int r = blockIdx.y;

    for (int i = t; i < NBUK; i += 512)
        gcur[i] = hist[(size_t)(r * NBUK + i) * NBLK + blockIdx.x];

    const int e0 = blockIdx.x * EPB;
    const int e1 = min(e0 + EPB, E);
    const int* sp = src + (size_t)r * E;
    const int* dp = dst + (size_t)r * E;
    const float* wp = ew + (size_t)r * E;

    for (int cb = e0; cb < e1; cb += CHK) {
        const int L = min(CHK, e1 - cb);
        for (int i = t; i < NBUK; i += 512) lcnt[i] = 0;
        __syncthreads();

        // Phase 1: stage + histogram (ew -> bf16 at stage time)
        if (L == CHK) {
            const i32x4* s4 = (const i32x4*)(sp + cb);
            const i32x4* d4 = (const i32x4*)(dp + cb);
            const f32x4* w4 = (const f32x4*)(wp + cb);
#pragma unroll
            for (int j = 0; j < CHK / 2048; ++j) {
                const int v = t + j * 512;
                const i32x4 d = __builtin_nontemporal_load(&d4[v]);
                const i32x4 s2 = __builtin_nontemporal_load(&s4[v]);
                const f32x4 w = __builtin_nontemporal_load(&w4[v]);
#pragma unroll
                for (int q = 0; q < 4; ++q) {
                    const int dd = (q == 0) ? d.x : (q == 1) ? d.y : (q == 2) ? d.z : d.w;
                    const int ss = (q == 0) ? s2.x : (q == 1) ? s2.y : (q == 2) ? s2.z : s2.w;
                    const float ww = (q == 0) ? w.x : (q == 1) ? w.y : (q == 2) ? w.z : w.w;
                    const int b = dd >> 8;
                    int2 p;
                    p.x = ss | ((dd & 255) << 20);
                    p.y = (int)f2bf(ww);
                    lrec[v * 4 + q] = p;
                    lbkt[v * 4 + q] = (short)b;
                    atomicAdd(&lcnt[b], 1);
                }
            }
        } else {
            for (int i = t; i < L; i += 512) {
                const int dd = dp[cb + i];
                const int ss = sp[cb + i];
                const float ww = wp[cb + i];
                const int b = dd >> 8;
                int2 p;
                p.x = ss | ((dd & 255) << 20);
                p.y = (int)f2bf(ww);
                lrec[i] = p;
                lbkt[i] = (short)b;
                atomicAdd(&lcnt[b], 1);
            }
        }
        __syncthreads();

        // Phase 2: Hillis-Steele scan of lcnt (391 entries) -> loff
        for (int off = 1; off < NBUK; off <<= 1) {
            int x = 0;
            if (t < NBUK && t >= off) x = lcnt[t - off];
            __syncthreads();
            if (t < NBUK) lcnt[t] += x;
            __syncthreads();
        }
        if (t < NBUK) loff[t + 1] = lcnt[t];
        if (t == 0) loff[0] = 0;
        __syncthreads();
        if (t < NBUK) lcnt[t] = loff[t];        // cursor = exclusive offsets
        __syncthreads();

        // Phase 3: counting-sort indices
        for (int i = t; i < L; i += 512) {
            const int b = lbkt[i];
            const int pos = atomicAdd(&lcnt[b], 1);
            lidx[pos] = i | (b << 16);
        }
        __syncthreads();

        // Phase 4: ordered write-out to both arrays (runs address-consecutive)
        for (int p = t; p < L; p += 512) {
            const int v = lidx[p];
            const int i = v & 0xFFFF;
            const int b = v >> 16;
            const int gpos = gcur[b] + (p - loff[b]);
            const int2 rec = lrec[i];
            sorted_sd[gpos] = rec.x;
            sorted_w[gpos] = (unsigned short)rec.y;
        }
        __syncthreads();

        // Advance running cursors
        for (int b = t; b < NBUK; b += 512)
            gcur[b] += loff[b + 1] - loff[b];
        __syncthreads();
    }
}

// ---------------------------------------------------------------------------
// Pull accumulate (R19/R25 champion + split 6B records): 1D grid 1568,
// XCD-affine decode. Two positional sub-passes over 34.5KB LDS. Per pass:
// stage {sd, bf16w} + 256-bin hist; scan; counting-sort lidx; 256 groups of
// 2 lanes (group = node, lane h = channels h*8..+7), 4-deep u16x8 gather
// pipeline. Registers + degree persist; one bf16 mean write -> part[r].
// ---------------------------------------------------------------------------
__global__ __launch_bounds__(512) void accum_kernel(const int* __restrict__ sorted_sd,
                                                    const unsigned short* __restrict__ sorted_w,
                                                    const u16x8* __restrict__ whb8,
                                                    const int* __restrict__ hist,
                                                    unsigned short* __restrict__ part) {
    __shared__ int2 lrec[CAP];                  // 26.6 KB: {sd, bf16w}
    __shared__ unsigned short lidx[CAP];        // 6.7 KB
    __shared__ int loff[BKN + 1];
    __shared__ int lcur[BKN];
    const int t = threadIdx.x;
    const int s  = blockIdx.x & 7;              // XCD slot
    const int r  = s >> 1;                      // etype -> XCDs {2r, 2r+1}
    const int ck = (blockIdx.x >> 3) * 2 + (s & 1);
    if (ck >= NBUK) return;
    const int g = t >> 1, h = t & 1;            // 256 groups of 2 lanes

    const int row = r * NBUK + ck;
    const int start = hist[(size_t)row * NBLK];
    const int end   = (row + 1 < NROWS) ? hist[(size_t)(row + 1) * NBLK] : TOT;
    const int L = end - start;
    int L0 = (L + 1) >> 1; if (L0 > CAP) L0 = CAP;
    int L1 = L - L0;       if (L1 > CAP) L1 = CAP;   // 15-sigma margin; never trimmed

    const int wbase = r * N;
    float a0 = 0.f, a1 = 0.f, a2 = 0.f, a3 = 0.f;
    float a4 = 0.f, a5 = 0.f, a6 = 0.f, a7 = 0.f;
    int deg = 0;

    int pbase = start;
    int plen  = L0;
#pragma unroll
    for (int pass = 0; pass < 2; ++pass) {
        if (t < BKN) lcur[t] = 0;
        __syncthreads();        // also guards lrec/lidx reuse vs previous pass

        // Phase 1: stage (two coalesced loads) + 256-bin histogram
        for (int i = t; i < plen; i += 512) {
            const int sd = __builtin_nontemporal_load(&sorted_sd[pbase + i]);
            const unsigned short w = __builtin_nontemporal_load(&sorted_w[pbase + i]);
            int2 p;
            p.x = sd;
            p.y = (int)w;
            lrec[i] = p;
            atomicAdd(&lcur[(sd >> 20) & 255], 1);
        }
        __syncthreads();

        // Phase 2: Hillis-Steele scan of lcur -> loff (uniform barriers)
        for (int off = 1; off < BKN; off <<= 1) {
            int x = 0;
            if (t < BKN && t >= off) x = lcur[t - off];
            __syncthreads();
            if (t < BKN) lcur[t] += x;
            __syncthreads();
        }
        if (t < BKN) loff[t + 1] = lcur[t];
        if (t == 0) loff[0] = 0;
        __syncthreads();
        if (t < BKN) lcur[t] = loff[t];
        __syncthreads();

        // Phase 3: counting-sort indices
        for (int i = t; i < plen; i += 512) {
            const int dl = (lrec[i].x >> 20) & 255;
            const int pos = atomicAdd(&lcur[dl], 1);
            lidx[pos] = (unsigned short)i;
        }
        __syncthreads();

        // Phase 4: group g = node g; lane h owns channels h*8..h*8+7.
        const int s0 = loff[g], e0 = loff[g + 1];
        deg += e0 - s0;

        int j = s0;
        for (; j + 4 <= e0; j += 4) {
            const int i0 = lidx[j], i1 = lidx[j + 1];
            const int i2 = lidx[j + 2], i3 = lidx[j + 3];
            const int2 r0 = lrec[i0], r1 = lrec[i1], r2 = lrec[i2], r3 = lrec[i3];
            const u16x8 u0 = whb8[(size_t)(wbase + (r0.x & 0xFFFFF)) * 2 + h];
            const u16x8 u1 = whb8[(size_t)(wbase + (r1.x & 0xFFFFF)) * 2 + h];
            const u16x8 u2 = whb8[(size_t)(wbase + (r2.x & 0xFFFFF)) * 2 + h];
            const u16x8 u3 = whb8[(size_t)(wbase + (r3.x & 0xFFFFF)) * 2 + h];
            const float w0 = bf2f((unsigned short)r0.y), w1 = bf2f((unsigned short)r1.y);
            const float w2 = bf2f((unsigned short)r2.y), w3 = bf2f((unsigned short)r3.y);
            a0 += bf2f(u0[0]) * w0 + bf2f(u1[0]) * w1 + bf2f(u2[0]) * w2 + bf2f(u3[0]) * w3;
            a1 += bf2f(u0[1]) * w0 + bf2f(u1[1]) * w1 + bf2f(u2[1]) * w2 + bf2f(u3[1]) * w3;
            a2 += bf2f(u0[2]) * w0 + bf2f(u1[2]) * w1 + bf2f(u2[2]) * w2 + bf2f(u3[2]) * w3;
            a3 += bf2f(u0[3]) * w0 + bf2f(u1[3]) * w1 + bf2f(u2[3]) * w2 + bf2f(u3[3]) * w3;
            a4 += bf2f(u0[4]) * w0 + bf2f(u1[4]) * w1 + bf2f(u2[4]) * w2 + bf2f(u3[4]) * w3;
            a5 += bf2f(u0[5]) * w0 + bf2f(u1[5]) * w1 + bf2f(u2[5]) * w2 + bf2f(u3[5]) * w3;
            a6 += bf2f(u0[6]) * w0 + bf2f(u1[6]) * w1 + bf2f(u2[6]) * w2 + bf2f(u3[6]) * w3;
            a7 += bf2f(u0[7]) * w0 + bf2f(u1[7]) * w1 + bf2f(u2[7]) * w2 + bf2f(u3[7]) * w3;
        }
        for (; j < e0; ++j) {
            const int2 r0 = lrec[lidx[j]];
            const u16x8 u0 = whb8[(size_t)(wbase + (r0.x & 0xFFFFF)) * 2 + h];
            const float w0 = bf2f((unsigned short)r0.y);
            a0 += bf2f(u0[0]) * w0; a1 += bf2f(u0[1]) * w0;
            a2 += bf2f(u0[2]) * w0; a3 += bf2f(u0[3]) * w0;
            a4 += bf2f(u0[4]) * w0; a5 += bf2f(u0[5]) * w0;
            a6 += bf2f(u0[6]) * w0; a7 += bf2f(u0[7]) * w0;
        }
        __syncthreads();   // all phase-4 reads done before next pass restages

        pbase += plen;
        plen = L1;
    }

    const int node = ck * BKN + g;
    if (node < N) {
        const float inv = (deg > 0) ? 1.f / (float)deg : 0.f;
        u16x8 v;
        v[0] = f2bf(a0 * inv); v[1] = f2bf(a1 * inv);
        v[2] = f2bf(a2 * inv); v[3] = f2bf(a3 * inv);
        v[4] = f2bf(a4 * inv); v[5] = f2bf(a5 * inv);
        v[6] = f2bf(a6 * inv); v[7] = f2bf(a7 * inv);
        *(u16x8*)&part[(size_t)(wbase + node) * 16 + h * 8] = v;
    }
}

// ---------------------------------------------------------------------------
// Finalize: out[n][c] = sum_r bf2f(part[r][n][c]).
// ---------------------------------------------------------------------------
__global__ void finalize_kernel(const unsigned short* __restrict__ part,
                                float* __restrict__ out) {
    const int i = blockIdx.x * blockDim.x + threadIdx.x;
    if (i >= N * 2) return;
    const int node = i >> 1, h = i & 1;
    const size_t off = (size_t)node * 16 + h * 8;
    float acc[8];
#pragma unroll
    for (int k = 0; k < 8; ++k) acc[k] = 0.f;
#pragma unroll
    for (int r = 0; r < R; ++r) {
        const u16x8 v = *(const u16x8*)&part[(size_t)r * N * 16 + off];
#pragma unroll
        for (int k = 0; k < 8; ++k) acc[k] += bf2f(v[k]);
    }
    float4 v0, v1;
    v0.x = acc[0]; v0.y = acc[1]; v0.z = acc[2]; v0.w = acc[3];
    v1.x = acc[4]; v1.y = acc[5]; v1.z = acc[6]; v1.w = acc[7];
    *(float4*)&out[off] = v0;
    *(float4*)&out[off + 4] = v1;
}

extern "C" void kernel_launch(void* const* d_in, const int* in_sizes, int n_in,
                              void* d_out, int out_size, void* d_ws, size_t ws_size,
                              hipStream_t stream) {
    const float* feat = (const float*)d_in[0];
    const int*   src  = (const int*)d_in[1];
    const int*   dst  = (const int*)d_in[2];
    const float* ew   = (const float*)d_in[3];
    const float* W    = (const float*)d_in[4];
    const float* b    = (const float*)d_in[5];
    float* out = (float*)d_out;

    // Workspace (bytes): [sorted_sd 32M][sorted_w 16M][wtb 64K][whb 12.8M]
    //                    [hist 770K][partials 1K][part bf16 12.8M]
    char* base = (char*)d_ws;
    int*            sorted_sd = (int*)base;            base += (size_t)TOT * 4;
    unsigned short* sorted_w  = (unsigned short*)base; base += (size_t)TOT * 2;
    short8*         wtb       = (short8*)base;         base += (size_t)64 * NCOL * 16;
    unsigned short* whb       = (unsigned short*)base; base += (size_t)R * N * C * 2;
    int*            hist      = (int*)base;            base += (size_t)HLEN * 4;
    int*            partials  = (int*)base;            base += (size_t)4096;
    unsigned short* part      = (unsigned short*)base;

    wt_kernel<<<8, 256, 0, stream>>>(W, wtb);
    gemm_kernel<<<(N + 63) / 64, 256, 0, stream>>>((const f32x4*)feat, wtb, b, whb);

    hist_kernel<<<dim3(NBLK, R), 256, 0, stream>>>(dst, hist);
    scan1_kernel<<<SCAN_NBLK, 256, 0, stream>>>(hist, partials);
    scan2_kernel<<<1, 1024, 0, stream>>>(partials, SCAN_NBLK);
    scan3_kernel<<<(HLEN + 255) / 256, 256, 0, stream>>>(hist, partials);

    scatter_kernel<<<dim3(NBLK, R), 512, 0, stream>>>(src, dst, ew, hist,
                                                      sorted_sd, sorted_w);
    accum_kernel<<<AGRID, 512, 0, stream>>>(sorted_sd, sorted_w,
                                            (const u16x8*)whb, hist, part);
    finalize_kernel<<<(N * 2 + 255) / 256, 256, 0, stream>>>(part, out);
}

// Round 28
// 172.296 us; speedup vs baseline: 1.0337x; 1.0337x over previous
//
#include <hip/hip_runtime.h>

constexpr int N = 100000;   // nodes
constexpr int E = 2000000;  // edges per etype
constexpr int D = 256;      // in dim
constexpr int C = 16;       // out dim
constexpr int R = 4;        // etypes
constexpr int NCOL = R * C;             // 64 fused gemm output columns
constexpr int TOT = R * E;              // 8M edges total

constexpr int BKN = 256;                       // nodes per coarse bucket
constexpr int NBUK = (N + BKN - 1) / BKN;      // 391 buckets
constexpr int EPB = 16384;                     // edges per sort block
constexpr int NBLK = (E + EPB - 1) / EPB;      // 123 sort blocks per etype
constexpr int NROWS = R * NBUK;                // 1564 hist rows
constexpr int HLEN = NROWS * NBLK;             // 192,372 hist entries
constexpr int SCAN_ELEMS = 2048;               // per scan1 block (256 thr x 8)
constexpr int SCAN_NBLK = (HLEN + SCAN_ELEMS - 1) / SCAN_ELEMS;  // 94
constexpr int CAP = 3328;                      // accum HALF-pass cap (15 sigma)
constexpr int CHK = 4096;                      // scatter chunk (records)
constexpr int AGRID = ((NBUK + 1) / 2) * 8;    // 1568 accum blocks (XCD-affine)

typedef __attribute__((ext_vector_type(8))) short short8;
typedef __attribute__((ext_vector_type(8))) unsigned short u16x8;
typedef __attribute__((ext_vector_type(4))) float f32x4;
typedef __attribute__((ext_vector_type(4))) int i32x4;

__device__ __forceinline__ float bf2f(unsigned short h) {
    return __uint_as_float(((unsigned int)h) << 16);
}
__device__ __forceinline__ unsigned short f2bf(float f) {
    unsigned int x = __float_as_uint(f);
    x += 0x7FFFu + ((x >> 16) & 1u);   // round-to-nearest-even
    return (unsigned short)(x >> 16);
}

// ---------------------------------------------------------------------------
// Pack W (R,D,C) + implicit fused-col layout into MFMA B-fragment order.
// ---------------------------------------------------------------------------
__global__ void wt_kernel(const float* __restrict__ W, short8* __restrict__ wtb) {
    const int idx = blockIdx.x * blockDim.x + threadIdx.x;
    if (idx >= 8 * 4 * 64) return;
    const int lane = idx & 63;
    const int ct   = (idx >> 6) & 3;
    const int ks   = idx >> 8;
    const int r = ct, c = lane & 15;
    const int kbase = ks * 32 + (lane >> 4) * 8;
    short8 v;
#pragma unroll
    for (int j = 0; j < 8; ++j)
        v[j] = (short)f2bf(W[(size_t)r * D * C + (size_t)(kbase + j) * C + c]);
    wtb[idx] = v;
}

// ---------------------------------------------------------------------------
// MFMA bf16 GEMM with LDS-staged A: whb[r][n][c] = bf16(feat@W_r + b_r).
// ---------------------------------------------------------------------------
__global__ __launch_bounds__(256) void gemm_kernel(
    const f32x4* __restrict__ feat4, const short8* __restrict__ wtb,
    const float* __restrict__ b, unsigned short* __restrict__ whb) {
    __shared__ unsigned short alds[64 * 272];   // 34.8 KB
    const int t   = threadIdx.x;
    const int n0  = blockIdx.x * 64;

#pragma unroll
    for (int j = 0; j < 16; ++j) {
        const int idx = t + j * 256;            // 0..4095
        const int row = idx >> 6, k4 = idx & 63;
        const int grow = n0 + row;
        const int lrow = (grow < N) ? grow : (N - 1);
        const f32x4 v = __builtin_nontemporal_load(&feat4[(size_t)lrow * 64 + k4]);
        ushort4 u;
        u.x = f2bf(v.x); u.y = f2bf(v.y); u.z = f2bf(v.z); u.w = f2bf(v.w);
        *(ushort4*)&alds[row * 272 + k4 * 4] = u;
    }
    __syncthreads();

    const int lane = t & 63;
    const int wv   = t >> 6;
    const int wrow = wv * 16 + (lane & 15);
    const int kblk = lane >> 4;

    f32x4 acc0 = {0.f, 0.f, 0.f, 0.f};
    f32x4 acc1 = acc0, acc2 = acc0, acc3 = acc0;

#pragma unroll
    for (int ks = 0; ks < 8; ++ks) {
        const short8 af = *(const short8*)&alds[wrow * 272 + ks * 32 + kblk * 8];
        const short8 b0 = wtb[(ks * 4 + 0) * 64 + lane];
        const short8 b1 = wtb[(ks * 4 + 1) * 64 + lane];
        const short8 b2 = wtb[(ks * 4 + 2) * 64 + lane];
        const short8 b3 = wtb[(ks * 4 + 3) * 64 + lane];
        acc0 = __builtin_amdgcn_mfma_f32_16x16x32_bf16(af, b0, acc0, 0, 0, 0);
        acc1 = __builtin_amdgcn_mfma_f32_16x16x32_bf16(af, b1, acc1, 0, 0, 0);
        acc2 = __builtin_amdgcn_mfma_f32_16x16x32_bf16(af, b2, acc2, 0, 0, 0);
        acc3 = __builtin_amdgcn_mfma_f32_16x16x32_bf16(af, b3, acc3, 0, 0, 0);
    }

    const int c    = lane & 15;
    const int rowb = n0 + wv * 16 + (lane >> 4) * 4;
    const float bias0 = b[ 0 + c];
    const float bias1 = b[16 + c];
    const float bias2 = b[32 + c];
    const float bias3 = b[48 + c];
#pragma unroll
    for (int reg = 0; reg < 4; ++reg) {
        const int gr = rowb + reg;
        if (gr < N) {
            whb[((size_t)0 * N + gr) * 16 + c] = f2bf(acc0[reg] + bias0);
            whb[((size_t)1 * N + gr) * 16 + c] = f2bf(acc1[reg] + bias1);
            whb[((size_t)2 * N + gr) * 16 + c] = f2bf(acc2[reg] + bias2);
            whb[((size_t)3 * N + gr) * 16 + c] = f2bf(acc3[reg] + bias3);
        }
    }
}

// ---------------------------------------------------------------------------
// Sort pass 1 (all etypes, one launch): per-block LDS histogram of dst>>8.
// Vector fast path; guarded scalar tail (123*16384 > E).
// ---------------------------------------------------------------------------
__global__ __launch_bounds__(256) void hist_kernel(const int* __restrict__ dst,
                                                   int* __restrict__ hist) {
    __shared__ int hcnt[NBUK];
    const int t = threadIdx.x;
    const int r = blockIdx.y;
    for (int i = t; i < NBUK; i += 256) hcnt[i] = 0;
    __syncthreads();
    const int e0 = blockIdx.x * EPB;
    if (E - e0 >= EPB) {
        const i32x4* d4 = (const i32x4*)(dst + (size_t)r * E + e0);
#pragma unroll
        for (int j = 0; j < EPB / 1024; ++j) {
            const i32x4 d = __builtin_nontemporal_load(&d4[t + j * 256]);
            atomicAdd(&hcnt[d.x >> 8], 1);
            atomicAdd(&hcnt[d.y >> 8], 1);
            atomicAdd(&hcnt[d.z >> 8], 1);
            atomicAdd(&hcnt[d.w >> 8], 1);
        }
    } else {
        const int* d = dst + (size_t)r * E;
        for (int e = e0 + t; e < E; e += 256)
            atomicAdd(&hcnt[d[e] >> 8], 1);
    }
    __syncthreads();
    for (int i = t; i < NBUK; i += 256)
        hist[(size_t)(r * NBUK + i) * NBLK + blockIdx.x] = hcnt[i];
}

// ---------------------------------------------------------------------------
// Global exclusive scan over HLEN entries (2048 per scan1 block).
// ---------------------------------------------------------------------------
__global__ __launch_bounds__(256) void scan1_kernel(int* __restrict__ data,
                                                    int* __restrict__ partials) {
    __shared__ int sh[256];
    const int t = threadIdx.x;
    const int idx = blockIdx.x * SCAN_ELEMS + t * 8;
    int v[8];
#pragma unroll
    for (int j = 0; j < 8; ++j)
        v[j] = (idx + j < HLEN) ? data[idx + j] : 0;
    int s = 0;
#pragma unroll
    for (int j = 0; j < 8; ++j) s += v[j];
    sh[t] = s;
    __syncthreads();
    for (int off = 1; off < 256; off <<= 1) {
        int x = (t >= off) ? sh[t - off] : 0;
        __syncthreads();
        sh[t] += x;
        __syncthreads();
    }
    int run = sh[t] - s;
    if (t == 255) partials[blockIdx.x] = sh[255];
#pragma unroll
    for (int j = 0; j < 8; ++j) {
        if (idx + j < HLEN) data[idx + j] = run;
        run += v[j];
    }
}

__global__ __launch_bounds__(1024) void scan2_kernel(int* __restrict__ partials, int n) {
    __shared__ int sh[1024];
    const int t = threadIdx.x;
    int a = (2 * t     < n) ? partials[2 * t]     : 0;
    int b = (2 * t + 1 < n) ? partials[2 * t + 1] : 0;
    const int s = a + b;
    sh[t] = s;
    __syncthreads();
    for (int off = 1; off < 1024; off <<= 1) {
        int x = (t >= off) ? sh[t - off] : 0;
        __syncthreads();
        sh[t] += x;
        __syncthreads();
    }
    const int excl = sh[t] - s;
    if (2 * t     < n) partials[2 * t]     = excl;
    if (2 * t + 1 < n) partials[2 * t + 1] = excl + a;
}

__global__ void scan3_kernel(int* __restrict__ data, const int* __restrict__ partials) {
    const int i = blockIdx.x * blockDim.x + threadIdx.x;
    if (i < HLEN) data[i] += partials[i / SCAN_ELEMS];
}

// ---------------------------------------------------------------------------
// Sort pass 2 (grid NBLK x R), chunk-sorted bursts (proven R13 config:
// CHK=4096, 391 coarse bins). Record: x = src | (dst&255)<<20 ; y = ew bits.
// ---------------------------------------------------------------------------
__global__ __launch_bounds__(512) void scatter_kernel(const int* __restrict__ src,
                                                      const int* __restrict__ dst,
                                                      const float* __restrict__ ew,
                                                      const int* __restrict__ hist,
                                                      int2* __restrict__ sorted) {
    __shared__ int2 lrec[CHK];                  // 32 KB
    __shared__ int  lidx[CHK];                  // 16 KB: i | b<<16
    __shared__ short lbkt[CHK];                 // 8 KB
    __shared__ int gcur[NBUK];                  // running global cursors
    __shared__ int loff[NBUK + 1];
    __shared__ int lcnt[NBUK];
    const int t = threadIdx.x;
    const int r = blockIdx.y;

    for (int i = t; i < NBUK; i += 512)
        gcur[i] = hist[(size_t)(r * NBUK + i) * NBLK + blockIdx.x];

    const int e0 = blockIdx.x * EPB;
    const int e1 = min(e0 + EPB, E);
    const int* sp = src + (size_t)r * E;
    const int* dp = dst + (size_t)r * E;
    const float* wp = ew + (size_t)r * E;

    for (int cb = e0; cb < e1; cb += CHK) {
        const int L = min(CHK, e1 - cb);
        for (int i = t; i < NBUK; i += 512) lcnt[i] = 0;
        __syncthreads();

        // Phase 1: stage + histogram
        if (L == CHK) {
            const i32x4* s4 = (const i32x4*)(sp + cb);
            const i32x4* d4 = (const i32x4*)(dp + cb);
            const f32x4* w4 = (const f32x4*)(wp + cb);
#pragma unroll
            for (int j = 0; j < CHK / 2048; ++j) {
                const int v = t + j * 512;
                const i32x4 d = __builtin_nontemporal_load(&d4[v]);
                const i32x4 s2 = __builtin_nontemporal_load(&s4[v]);
                const f32x4 w = __builtin_nontemporal_load(&w4[v]);
#pragma unroll
                for (int q = 0; q < 4; ++q) {
                    const int dd = (q == 0) ? d.x : (q == 1) ? d.y : (q == 2) ? d.z : d.w;
                    const int ss = (q == 0) ? s2.x : (q == 1) ? s2.y : (q == 2) ? s2.z : s2.w;
                    const float ww = (q == 0) ? w.x : (q == 1) ? w.y : (q == 2) ? w.z : w.w;
                    const int b = dd >> 8;
                    int2 p;
                    p.x = ss | ((dd & 255) << 20);
                    p.y = __float_as_int(ww);
                    lrec[v * 4 + q] = p;
                    lbkt[v * 4 + q] = (short)b;
                    atomicAdd(&lcnt[b], 1);
                }
            }
        } else {
            for (int i = t; i < L; i += 512) {
                const int dd = dp[cb + i];
                const int ss = sp[cb + i];
                const float ww = wp[cb + i];
                const int b = dd >> 8;
                int2 p;
                p.x = ss | ((dd & 255) << 20);
                p.y = __float_as_int(ww);
                lrec[i] = p;
                lbkt[i] = (short)b;
                atomicAdd(&lcnt[b], 1);
            }
        }
        __syncthreads();

        // Phase 2: Hillis-Steele scan of lcnt (391 entries) -> loff
        for (int off = 1; off < NBUK; off <<= 1) {
            int x = 0;
            if (t < NBUK && t >= off) x = lcnt[t - off];
            __syncthreads();
            if (t < NBUK) lcnt[t] += x;
            __syncthreads();
        }
        if (t < NBUK) loff[t + 1] = lcnt[t];
        if (t == 0) loff[0] = 0;
        __syncthreads();
        if (t < NBUK) lcnt[t] = loff[t];        // cursor = exclusive offsets
        __syncthreads();

        // Phase 3: counting-sort indices
        for (int i = t; i < L; i += 512) {
            const int b = lbkt[i];
            const int pos = atomicAdd(&lcnt[b], 1);
            lidx[pos] = i | (b << 16);
        }
        __syncthreads();

        // Phase 4: ordered write-out (bucket runs address-consecutive)
        for (int p = t; p < L; p += 512) {
            const int v = lidx[p];
            const int i = v & 0xFFFF;
            const int b = v >> 16;
            sorted[gcur[b] + (p - loff[b])] = lrec[i];
        }
        __syncthreads();

        // Advance running cursors
        for (int b = t; b < NBUK; b += 512)
            gcur[b] += loff[b + 1] - loff[b];
        __syncthreads();
    }
}

// ---------------------------------------------------------------------------
// Pull accumulate (R19/R25 champion): 1D grid 1568, XCD-affine decode —
// s = bid&7 -> XCD; etype r = s>>1, bucket ck = (bid>>3)*2 + (s&1). Each XCD
// touches only whb_r (3.2MB < 4MB L2). Two positional sub-passes over 34.5KB
// LDS. Per sub-pass: stage + 256-bin hist; scan; counting-sort lidx; 256
// groups of 2 lanes (group = node, lane h = channels h*8..+7), 4-deep u16x8
// gather pipeline. Registers + degree persist; one bf16 mean write -> part[r].
// ---------------------------------------------------------------------------
__global__ __launch_bounds__(512) void accum_kernel(const int2* __restrict__ sorted,
                                                    const u16x8* __restrict__ whb8,
                                                    const int* __restrict__ hist,
                                                    unsigned short* __restrict__ part) {
    __shared__ int2 lrec[CAP];                  // 26.6 KB
    __shared__ unsigned short lidx[CAP];        // 6.7 KB
    __shared__ int loff[BKN + 1];
    __shared__ int lcur[BKN];
    const int t = threadIdx.x;
    const int s  = blockIdx.x & 7;              // XCD slot
    const int r  = s >> 1;                      // etype -> XCDs {2r, 2r+1}
    const int ck = (blockIdx.x >> 3) * 2 + (s & 1);
    if (ck >= NBUK) return;
    const int g = t >> 1, h = t & 1;            // 256 groups of 2 lanes

    const int row = r * NBUK + ck;
    const int start = hist[(size_t)row * NBLK];
    const int end   = (row + 1 < NROWS) ? hist[(size_t)(row + 1) * NBLK] : TOT;
    const int L = end - start;
    int L0 = (L + 1) >> 1; if (L0 > CAP) L0 = CAP;
    int L1 = L - L0;       if (L1 > CAP) L1 = CAP;   // 15-sigma margin; never trimmed

    const int wbase = r * N;
    float a0 = 0.f, a1 = 0.f, a2 = 0.f, a3 = 0.f;
    float a4 = 0.f, a5 = 0.f, a6 = 0.f, a7 = 0.f;
    int deg = 0;

    int pbase = start;
    int plen  = L0;
#pragma unroll
    for (int pass = 0; pass < 2; ++pass) {
        if (t < BKN) lcur[t] = 0;
        __syncthreads();        // also guards lrec/lidx reuse vs previous pass

        // Phase 1: stage + 256-bin histogram (single global read)
        for (int i = t; i < plen; i += 512) {
            long long raw = __builtin_nontemporal_load((const long long*)&sorted[pbase + i]);
            int2 p = *(int2*)&raw;
            lrec[i] = p;
            atomicAdd(&lcur[(p.x >> 20) & 255], 1);
        }
        __syncthreads();

        // Phase 2: Hillis-Steele scan of lcur -> loff (uniform barriers)
        for (int off = 1; off < BKN; off <<= 1) {
            int x = 0;
            if (t < BKN && t >= off) x = lcur[t - off];
            __syncthreads();
            if (t < BKN) lcur[t] += x;
            __syncthreads();
        }
        if (t < BKN) loff[t + 1] = lcur[t];
        if (t == 0) loff[0] = 0;
        __syncthreads();
        if (t < BKN) lcur[t] = loff[t];
        __syncthreads();

        // Phase 3: counting-sort indices
        for (int i = t; i < plen; i += 512) {
            const int dl = (lrec[i].x >> 20) & 255;
            const int pos = atomicAdd(&lcur[dl], 1);
            lidx[pos] = (unsigned short)i;
        }
        __syncthreads();

        // Phase 4: group g = node g; lane h owns channels h*8..h*8+7.
        const int s0 = loff[g], e0 = loff[g + 1];
        deg += e0 - s0;

        int j = s0;
        for (; j + 4 <= e0; j += 4) {
            const int i0 = lidx[j], i1 = lidx[j + 1];
            const int i2 = lidx[j + 2], i3 = lidx[j + 3];
            const int2 r0 = lrec[i0], r1 = lrec[i1], r2 = lrec[i2], r3 = lrec[i3];
            const u16x8 u0 = whb8[(size_t)(wbase + (r0.x & 0xFFFFF)) * 2 + h];
            const u16x8 u1 = whb8[(size_t)(wbase + (r1.x & 0xFFFFF)) * 2 + h];
            const u16x8 u2 = whb8[(size_t)(wbase + (r2.x & 0xFFFFF)) * 2 + h];
            const u16x8 u3 = whb8[(size_t)(wbase + (r3.x & 0xFFFFF)) * 2 + h];
            const float w0 = __int_as_float(r0.y), w1 = __int_as_float(r1.y);
            const float w2 = __int_as_float(r2.y), w3 = __int_as_float(r3.y);
            a0 += bf2f(u0[0]) * w0 + bf2f(u1[0]) * w1 + bf2f(u2[0]) * w2 + bf2f(u3[0]) * w3;
            a1 += bf2f(u0[1]) * w0 + bf2f(u1[1]) * w1 + bf2f(u2[1]) * w2 + bf2f(u3[1]) * w3;
            a2 += bf2f(u0[2]) * w0 + bf2f(u1[2]) * w1 + bf2f(u2[2]) * w2 + bf2f(u3[2]) * w3;
            a3 += bf2f(u0[3]) * w0 + bf2f(u1[3]) * w1 + bf2f(u2[3]) * w2 + bf2f(u3[3]) * w3;
            a4 += bf2f(u0[4]) * w0 + bf2f(u1[4]) * w1 + bf2f(u2[4]) * w2 + bf2f(u3[4]) * w3;
            a5 += bf2f(u0[5]) * w0 + bf2f(u1[5]) * w1 + bf2f(u2[5]) * w2 + bf2f(u3[5]) * w3;
            a6 += bf2f(u0[6]) * w0 + bf2f(u1[6]) * w1 + bf2f(u2[6]) * w2 + bf2f(u3[6]) * w3;
            a7 += bf2f(u0[7]) * w0 + bf2f(u1[7]) * w1 + bf2f(u2[7]) * w2 + bf2f(u3[7]) * w3;
        }
        for (; j < e0; ++j) {
            const int2 r0 = lrec[lidx[j]];
            const u16x8 u0 = whb8[(size_t)(wbase + (r0.x & 0xFFFFF)) * 2 + h];
            const float w0 = __int_as_float(r0.y);
            a0 += bf2f(u0[0]) * w0; a1 += bf2f(u0[1]) * w0;
            a2 += bf2f(u0[2]) * w0; a3 += bf2f(u0[3]) * w0;
            a4 += bf2f(u0[4]) * w0; a5 += bf2f(u0[5]) * w0;
            a6 += bf2f(u0[6]) * w0; a7 += bf2f(u0[7]) * w0;
        }
        __syncthreads();   // all phase-4 reads done before next pass restages

        pbase += plen;
        plen = L1;
    }

    const int node = ck * BKN + g;
    if (node < N) {
        const float inv = (deg > 0) ? 1.f / (float)deg : 0.f;
        u16x8 v;
        v[0] = f2bf(a0 * inv); v[1] = f2bf(a1 * inv);
        v[2] = f2bf(a2 * inv); v[3] = f2bf(a3 * inv);
        v[4] = f2bf(a4 * inv); v[5] = f2bf(a5 * inv);
        v[6] = f2bf(a6 * inv); v[7] = f2bf(a7 * inv);
        *(u16x8*)&part[(size_t)(wbase + node) * 16 + h * 8] = v;
    }
}

// ---------------------------------------------------------------------------
// Finalize: out[n][c] = sum_r bf2f(part[r][n][c]). Thread -> (node, half):
// reads 4 x u16x8 (16B each), sums in f32, writes 2 coalesced float4s.
// ---------------------------------------------------------------------------
__global__ void finalize_kernel(const unsigned short* __restrict__ part,
                                float* __restrict__ out) {
    const int i = blockIdx.x * blockDim.x + threadIdx.x;
    if (i >= N * 2) return;
    const int node = i >> 1, h = i & 1;
    const size_t off = (size_t)node * 16 + h * 8;
    float acc[8];
#pragma unroll
    for (int k = 0; k < 8; ++k) acc[k] = 0.f;
#pragma unroll
    for (int r = 0; r < R; ++r) {
        const u16x8 v = *(const u16x8*)&part[(size_t)r * N * 16 + off];
#pragma unroll
        for (int k = 0; k < 8; ++k) acc[k] += bf2f(v[k]);
    }
    float4 v0, v1;
    v0.x = acc[0]; v0.y = acc[1]; v0.z = acc[2]; v0.w = acc[3];
    v1.x = acc[4]; v1.y = acc[5]; v1.z = acc[6]; v1.w = acc[7];
    *(float4*)&out[off] = v0;
    *(float4*)&out[off + 4] = v1;
}

extern "C" void kernel_launch(void* const* d_in, const int* in_sizes, int n_in,
                              void* d_out, int out_size, void* d_ws, size_t ws_size,
                              hipStream_t stream) {
    const float* feat = (const float*)d_in[0];
    const int*   src  = (const int*)d_in[1];
    const int*   dst  = (const int*)d_in[2];
    const float* ew   = (const float*)d_in[3];
    const float* W    = (const float*)d_in[4];
    const float* b    = (const float*)d_in[5];
    float* out = (float*)d_out;

    // Workspace (bytes):
    // [sorted 64M][wtb 64K][whb bf16 12.8M][hist 770K][partials 1K][part bf16 12.8M]
    char* base = (char*)d_ws;
    int2*           sorted   = (int2*)base;           base += (size_t)TOT * 8;
    short8*         wtb      = (short8*)base;         base += (size_t)64 * NCOL * 16;
    unsigned short* whb      = (unsigned short*)base; base += (size_t)R * N * C * 2;
    int*            hist     = (int*)base;            base += (size_t)HLEN * 4;
    int*            partials = (int*)base;            base += (size_t)4096;
    unsigned short* part     = (unsigned short*)base;

    wt_kernel<<<8, 256, 0, stream>>>(W, wtb);
    gemm_kernel<<<(N + 63) / 64, 256, 0, stream>>>((const f32x4*)feat, wtb, b, whb);

    hist_kernel<<<dim3(NBLK, R), 256, 0, stream>>>(dst, hist);
    scan1_kernel<<<SCAN_NBLK, 256, 0, stream>>>(hist, partials);
    scan2_kernel<<<1, 1024, 0, stream>>>(partials, SCAN_NBLK);
    scan3_kernel<<<(HLEN + 255) / 256, 256, 0, stream>>>(hist, partials);

    scatter_kernel<<<dim3(NBLK, R), 512, 0, stream>>>(src, dst, ew, hist, sorted);
    accum_kernel<<<AGRID, 512, 0, stream>>>(sorted, (const u16x8*)whb, hist, part);
    finalize_kernel<<<(N * 2 + 255) / 256, 256, 0, stream>>>(part, out);
}